// Round 10
// baseline (134.838 us; speedup 1.0000x reference)
//
#include <hip/hip_runtime.h>
#include <math.h>

// Problem constants
constexpr int B_ = 8;
constexpr int N_ = 400;
constexpr int D_ = 768;
constexpr int M_ = 160;                 // int(0.4 * 400)
constexpr int PAIRS_ = M_ * (M_ - 1);   // 25440

typedef __attribute__((ext_vector_type(8))) short short8;   // 8 bf16 (4 VGPRs)
typedef __attribute__((ext_vector_type(4))) float floatx4;  // MFMA C/D

// Workspace layout (bytes), tiny (~105 KB):
//   z     : double[B_*N_]     @ 0
//   pos   : int[B_*M_]        @ 25600
//   aterm : float[B_*N_*3]    @ 30720   (raw-row indexed; includes b_pair)
//   bterm : float[B_*N_*3]    @ 69120
//   done  : unsigned[8]       @ 107520  (per-batch arrival counters; memset 0)

// ---------------------------------------------------------------------------
// Kernel 1 (span + ab + in-place rank). One wave per row (4 rows/block; the
// 100 blocks of batch b are blockIdx 100b..100b+99). Per row:
//   z = fp64 dot(x, w_span)           (sigmoid monotonic -> rank on z)
//   aterm[row,c] = dot(x, w1[:,c]) + b_pair[c];  bterm[row,c] = dot(x, w2[:,c])
// Then each block releases done[b]; the 100th arrival (acq_rel, agent scope —
// same fence pattern as R6's verified grid barrier) computes batch b's
// ranking: pos = sorted ascending of stable descending ranks of z[i], i<M.
__global__ __launch_bounds__(256) void k_span_rank(const float* __restrict__ x,
                                                   const float* __restrict__ w_span,
                                                   const float* __restrict__ w_pair,
                                                   const float* __restrict__ b_pair,
                                                   double* __restrict__ z,
                                                   float* __restrict__ aterm,
                                                   float* __restrict__ bterm,
                                                   unsigned* __restrict__ done,
                                                   int* __restrict__ pos) {
  __shared__ double zsh[N_];
  __shared__ int ranksh[M_];
  __shared__ int winner;

  int row = blockIdx.x * 4 + (threadIdx.x >> 6);  // 0..B*N-1
  int lane = threadIdx.x & 63;
  int b = blockIdx.x / 100;                       // 4 rows/block, 400 rows/batch
  const float* xr = x + (size_t)row * D_;

  double acc = 0.0;
  float a0 = 0, a1 = 0, a2 = 0, c0 = 0, c1 = 0, c2 = 0;
#pragma unroll
  for (int it = 0; it < 3; ++it) {
    int d = it * 256 + lane * 4;
    float4 xv = *(const float4*)(xr + d);
    float4 sv = *(const float4*)(w_span + d);
    acc += (double)xv.x * sv.x + (double)xv.y * sv.y +
           (double)xv.z * sv.z + (double)xv.w * sv.w;
    float xf[4] = {xv.x, xv.y, xv.z, xv.w};

    float w1v[12], w2v[12];
#pragma unroll
    for (int q = 0; q < 3; ++q) {
      *(float4*)(w1v + 4 * q) = *(const float4*)(w_pair + (size_t)d * 3 + 4 * q);
      *(float4*)(w2v + 4 * q) = *(const float4*)(w_pair + (size_t)(D_ + d) * 3 + 4 * q);
    }
#pragma unroll
    for (int e = 0; e < 4; ++e) {
      a0 += xf[e] * w1v[e * 3 + 0];
      a1 += xf[e] * w1v[e * 3 + 1];
      a2 += xf[e] * w1v[e * 3 + 2];
      c0 += xf[e] * w2v[e * 3 + 0];
      c1 += xf[e] * w2v[e * 3 + 1];
      c2 += xf[e] * w2v[e * 3 + 2];
    }
  }
#pragma unroll
  for (int off = 32; off > 0; off >>= 1) {
    acc += __shfl_down(acc, off, 64);
    a0 += __shfl_down(a0, off, 64);
    a1 += __shfl_down(a1, off, 64);
    a2 += __shfl_down(a2, off, 64);
    c0 += __shfl_down(c0, off, 64);
    c1 += __shfl_down(c1, off, 64);
    c2 += __shfl_down(c2, off, 64);
  }
  if (lane == 0) {
    z[row] = acc;
    aterm[row * 3 + 0] = a0 + b_pair[0];
    aterm[row * 3 + 1] = a1 + b_pair[1];
    aterm[row * 3 + 2] = a2 + b_pair[2];
    bterm[row * 3 + 0] = c0;
    bterm[row * 3 + 1] = c1;
    bterm[row * 3 + 2] = c2;
  }

  // ---- last-block-per-batch does the rank, overlapped with other batches ----
  __syncthreads();  // all 4 waves' z/aterm/bterm stores issued & drained
  if (threadIdx.x == 0) {
    __threadfence();  // agent-scope release: write back this XCD's L2 to LLC
    unsigned old = __hip_atomic_fetch_add(done + b, 1u, __ATOMIC_ACQ_REL,
                                          __HIP_MEMORY_SCOPE_AGENT);
    winner = (old == 99u);
    if (winner) __threadfence();  // acquire side: invalidate stale L1/L2 lines
  }
  __syncthreads();
  if (!winner) return;

  int t = threadIdx.x;
  for (int j = t; j < N_; j += 256) zsh[j] = z[b * N_ + j];
  __syncthreads();
  if (t < M_) {
    double zi = zsh[t];
    int cnt = 0;
    for (int j = 0; j < N_; ++j) {
      double zj = zsh[j];
      cnt += (zj > zi) || (zj == zi && j < t);
    }
    ranksh[t] = cnt;
  }
  __syncthreads();
  if (t < M_) {
    int r = ranksh[t];
    int slot = 0;
#pragma unroll 8
    for (int k = 0; k < M_; ++k) slot += (ranksh[k] < r);
    pos[b * M_ + slot] = r;  // ranks distinct -> ascending sort
  }
}

// ---------------------------------------------------------------------------
// Kernel 2 (MFMA pairs, direct from fp32 x — byte-identical to R9's k_pairs).
// One BLOCK per (b, 16x16 tile); 4 waves split K (192 each = 6 steps).
// Per K=32 step: load 8 fp32 of x_i, 8 of x_j, 24 of w3; truncate-convert
// to bf16 in-register; 3 MFMA. LDS-reduce partials (stride-13 pad), wave 0
// epilogue: +aterm+bterm, sigmoid -> softmax over C=3, write probs + ranges.
__global__ __launch_bounds__(256) void k_pairs(const float* __restrict__ x,
                                               const float* __restrict__ w_pair,
                                               const int* __restrict__ pos,
                                               const float* __restrict__ aterm,
                                               const float* __restrict__ bterm,
                                               const int* __restrict__ span_ranges,
                                               float* __restrict__ out_probs,
                                               float4* __restrict__ out_ranges) {
  __shared__ float red[3 * 64 * 13];  // partials of waves 1..3, padded

  int lane = threadIdx.x & 63;
  int wv = threadIdx.x >> 6;          // wave in block: K-chunk index
  int blk = blockIdx.x;               // 0..799
  int b = blk / 100;
  int t = blk - b * 100;
  int ti = t / 10;                    // i-tile (rows; A side = x_i .* w3_c)
  int tj = t - ti * 10;               // j-tile (cols; B side = x_j)
  int quad = lane >> 4;
  int l16 = lane & 15;

  const int* posb = pos + b * M_;
  int pa = posb[ti * 16 + l16];
  int pb = posb[tj * 16 + l16];
  const float* xa = x + ((size_t)(b * N_ + pa)) * D_ + wv * 192 + quad * 8;
  const float* xb = x + ((size_t)(b * N_ + pb)) * D_ + wv * 192 + quad * 8;
  const float* w3 = w_pair + 2 * D_ * 3;

  floatx4 acc0 = {0.f, 0.f, 0.f, 0.f};
  floatx4 acc1 = {0.f, 0.f, 0.f, 0.f};
  floatx4 acc2 = {0.f, 0.f, 0.f, 0.f};

#pragma unroll
  for (int k = 0; k < 192; k += 32) {
    float af[8], bfv[8], wv24[24];
    *(float4*)(af + 0) = *(const float4*)(xa + k + 0);
    *(float4*)(af + 4) = *(const float4*)(xa + k + 4);
    *(float4*)(bfv + 0) = *(const float4*)(xb + k + 0);
    *(float4*)(bfv + 4) = *(const float4*)(xb + k + 4);
    const float* wp = w3 + (size_t)(wv * 192 + k + quad * 8) * 3;
#pragma unroll
    for (int q = 0; q < 6; ++q) *(float4*)(wv24 + 4 * q) = *(const float4*)(wp + 4 * q);

    short8 bh;
#pragma unroll
    for (int e = 0; e < 8; ++e) bh[e] = (short)(__float_as_uint(bfv[e]) >> 16);

#pragma unroll
    for (int c = 0; c < 3; ++c) {
      short8 h;
#pragma unroll
      for (int e = 0; e < 8; ++e)
        h[e] = (short)(__float_as_uint(af[e] * wv24[e * 3 + c]) >> 16);
      floatx4 acc = (c == 0) ? acc0 : (c == 1) ? acc1 : acc2;
      acc = __builtin_amdgcn_mfma_f32_16x16x32_bf16(h, bh, acc, 0, 0, 0);
      if (c == 0) acc0 = acc; else if (c == 1) acc1 = acc; else acc2 = acc;
    }
  }

  // Cross-wave reduction: waves 1..3 park partials in LDS, wave 0 sums.
  if (wv > 0) {
    int base = ((wv - 1) * 64 + lane) * 13;
#pragma unroll
    for (int r = 0; r < 4; ++r) {
      red[base + r] = acc0[r];
      red[base + 4 + r] = acc1[r];
      red[base + 8 + r] = acc2[r];
    }
  }
  __syncthreads();
  if (wv != 0) return;

#pragma unroll
  for (int u = 0; u < 3; ++u) {
    int base = (u * 64 + lane) * 13;
#pragma unroll
    for (int r = 0; r < 4; ++r) {
      acc0[r] += red[base + r];
      acc1[r] += red[base + 4 + r];
      acc2[r] += red[base + 8 + r];
    }
  }

  // Epilogue. C/D layout: col = lane&15 (j), row = quad*4 + reg (i).
  const float* at = aterm + (size_t)(b * N_) * 3;
  const float* bt = bterm + (size_t)(b * N_) * 3;
  int j = tj * 16 + l16;
  float bj0 = bt[pb * 3 + 0], bj1 = bt[pb * 3 + 1], bj2 = bt[pb * 3 + 2];
  int rj0 = span_ranges[pb * 2 + 0], rj1 = span_ranges[pb * 2 + 1];

#pragma unroll
  for (int r = 0; r < 4; ++r) {
    int i = ti * 16 + quad * 4 + r;
    if (i == j) continue;
    int pi = posb[i];
    float l0 = acc0[r] + at[pi * 3 + 0] + bj0;
    float l1 = acc1[r] + at[pi * 3 + 1] + bj1;
    float l2 = acc2[r] + at[pi * 3 + 2] + bj2;
    float s0 = 1.0f / (1.0f + expf(-l0));
    float s1 = 1.0f / (1.0f + expf(-l1));
    float s2 = 1.0f / (1.0f + expf(-l2));
    float e0 = expf(s0), e1 = expf(s1), e2 = expf(s2);
    float inv = 1.0f / (e0 + e1 + e2);
    int jj = j - (j > i ? 1 : 0);
    size_t p = (size_t)b * PAIRS_ + (size_t)i * (M_ - 1) + jj;
    out_probs[p * 3 + 0] = e0 * inv;
    out_probs[p * 3 + 1] = e1 * inv;
    out_probs[p * 3 + 2] = e2 * inv;
    float4 rg;
    rg.x = (float)span_ranges[pi * 2 + 0];
    rg.y = (float)span_ranges[pi * 2 + 1];
    rg.z = (float)rj0;
    rg.w = (float)rj1;
    out_ranges[p] = rg;
  }
}

// ---------------------------------------------------------------------------
extern "C" void kernel_launch(void* const* d_in, const int* in_sizes, int n_in,
                              void* d_out, int out_size, void* d_ws, size_t ws_size,
                              hipStream_t stream) {
  const float* x = (const float*)d_in[0];
  const float* w_span = (const float*)d_in[1];
  // d_in[2] = b_span: constant shift, irrelevant to the ranking -> unused.
  const float* w_pair = (const float*)d_in[3];
  const float* b_pair = (const float*)d_in[4];
  const int* span_ranges = (const int*)d_in[5];

  char* ws = (char*)d_ws;
  double* z = (double*)ws;
  int* pos = (int*)(ws + 25600);
  float* aterm = (float*)(ws + 30720);
  float* bterm = (float*)(ws + 69120);
  unsigned* done = (unsigned*)(ws + 107520);

  float* out = (float*)d_out;
  float* out_probs = out;                                         // B*P*3 floats
  float4* out_ranges = (float4*)(out + (size_t)B_ * PAIRS_ * 3);  // B*P*4 floats

  // done[] must start at 0 (ws is poisoned 0xAA before every launch).
  hipMemsetAsync(done, 0, 32, stream);
  k_span_rank<<<(B_ * N_) / 4, 256, 0, stream>>>(x, w_span, w_pair, b_pair, z,
                                                 aterm, bterm, done, pos);
  k_pairs<<<B_ * 100, 256, 0, stream>>>(x, w_pair, pos, aterm, bterm,
                                        span_ranges, out_probs, out_ranges);
}

// Round 11
// 106.172 us; speedup vs baseline: 1.2700x; 1.2700x over previous
//
#include <hip/hip_runtime.h>
#include <math.h>

// Problem constants
constexpr int B_ = 8;
constexpr int N_ = 400;
constexpr int D_ = 768;
constexpr int M_ = 160;                 // int(0.4 * 400)
constexpr int PAIRS_ = M_ * (M_ - 1);   // 25440

typedef __attribute__((ext_vector_type(8))) short short8;   // 8 bf16 (4 VGPRs)
typedef __attribute__((ext_vector_type(4))) float floatx4;  // MFMA C/D

// Workspace layout (bytes), tiny (~64 KB):
//   z     : double[B_*N_]     @ 0
//   pos   : int[B_*M_]        @ 25600
//   aterm : float[B_*N_*3]    @ 30720   (raw-row indexed; includes b_pair)
//   bterm : float[B_*N_*3]    @ 69120
//
// NOTE (R10 lesson): do NOT replace the dispatch boundaries with in-kernel
// agent-scope fences — on gfx950 each agent-scope release fence drains the
// XCD's L2 (R6: 142 us @ 1.7% VALUBusy; R10: 52 us @ 2% VALUBusy). The
// kernel->kernel dispatch boundary provides cross-XCD visibility for free.

// ---------------------------------------------------------------------------
// Kernel 1 (span + ab, ALL rows — no pos dependency, full parallelism).
// One wave per row:
//   z = fp64 dot(x, w_span)           (sigmoid monotonic -> rank on z)
//   aterm[row,c] = dot(x, w1[:,c]) + b_pair[c];  bterm[row,c] = dot(x, w2[:,c])
__global__ __launch_bounds__(256) void k_span_ab(const float* __restrict__ x,
                                                 const float* __restrict__ w_span,
                                                 const float* __restrict__ w_pair,
                                                 const float* __restrict__ b_pair,
                                                 double* __restrict__ z,
                                                 float* __restrict__ aterm,
                                                 float* __restrict__ bterm) {
  int row = blockIdx.x * 4 + (threadIdx.x >> 6);  // 0..B*N-1
  int lane = threadIdx.x & 63;
  const float* xr = x + (size_t)row * D_;

  double acc = 0.0;
  float a0 = 0, a1 = 0, a2 = 0, c0 = 0, c1 = 0, c2 = 0;
#pragma unroll
  for (int it = 0; it < 3; ++it) {
    int d = it * 256 + lane * 4;
    float4 xv = *(const float4*)(xr + d);
    float4 sv = *(const float4*)(w_span + d);
    acc += (double)xv.x * sv.x + (double)xv.y * sv.y +
           (double)xv.z * sv.z + (double)xv.w * sv.w;
    float xf[4] = {xv.x, xv.y, xv.z, xv.w};

    float w1v[12], w2v[12];
#pragma unroll
    for (int q = 0; q < 3; ++q) {
      *(float4*)(w1v + 4 * q) = *(const float4*)(w_pair + (size_t)d * 3 + 4 * q);
      *(float4*)(w2v + 4 * q) = *(const float4*)(w_pair + (size_t)(D_ + d) * 3 + 4 * q);
    }
#pragma unroll
    for (int e = 0; e < 4; ++e) {
      a0 += xf[e] * w1v[e * 3 + 0];
      a1 += xf[e] * w1v[e * 3 + 1];
      a2 += xf[e] * w1v[e * 3 + 2];
      c0 += xf[e] * w2v[e * 3 + 0];
      c1 += xf[e] * w2v[e * 3 + 1];
      c2 += xf[e] * w2v[e * 3 + 2];
    }
  }
#pragma unroll
  for (int off = 32; off > 0; off >>= 1) {
    acc += __shfl_down(acc, off, 64);
    a0 += __shfl_down(a0, off, 64);
    a1 += __shfl_down(a1, off, 64);
    a2 += __shfl_down(a2, off, 64);
    c0 += __shfl_down(c0, off, 64);
    c1 += __shfl_down(c1, off, 64);
    c2 += __shfl_down(c2, off, 64);
  }
  if (lane == 0) {
    z[row] = acc;
    aterm[row * 3 + 0] = a0 + b_pair[0];
    aterm[row * 3 + 1] = a1 + b_pair[1];
    aterm[row * 3 + 2] = a2 + b_pair[2];
    bterm[row * 3 + 0] = c0;
    bterm[row * 3 + 1] = c1;
    bterm[row * 3 + 2] = c2;
  }
}

// ---------------------------------------------------------------------------
// Kernel 2: per batch, rank[i] (i<M) = stable descending rank of z[i];
// pos = sorted ascending of those ranks. One block per batch (tiny).
__global__ __launch_bounds__(256) void k_rank(const double* __restrict__ z,
                                              int* __restrict__ pos) {
  __shared__ double zsh[N_];
  __shared__ int ranksh[M_];
  int b = blockIdx.x;
  int t = threadIdx.x;
  for (int j = t; j < N_; j += 256) zsh[j] = z[b * N_ + j];
  __syncthreads();
  if (t < M_) {
    double zi = zsh[t];
    int cnt = 0;
    for (int j = 0; j < N_; ++j) {
      double zj = zsh[j];
      cnt += (zj > zi) || (zj == zi && j < t);
    }
    ranksh[t] = cnt;
  }
  __syncthreads();
  if (t < M_) {
    int r = ranksh[t];
    int slot = 0;
#pragma unroll 8
    for (int k = 0; k < M_; ++k) slot += (ranksh[k] < r);
    pos[b * M_ + slot] = r;  // ranks distinct -> ascending sort
  }
}

// ---------------------------------------------------------------------------
// Kernel 3 (MFMA pairs, direct from fp32 x — no prepped intermediates).
// One BLOCK per (b, 16x16 tile); 4 waves split K (192 each = 6 steps).
// Per K=32 step: load 8 fp32 of x_i, 8 of x_j, 24 of w3; truncate-convert
// to bf16 in-register (error budget 200x); 3 MFMA. LDS-reduce partials
// (stride-13 pad = 2 lanes/bank, free), wave 0 epilogue:
// +aterm+bterm, sigmoid -> softmax over C=3, write probs + ranges.
__global__ __launch_bounds__(256) void k_pairs(const float* __restrict__ x,
                                               const float* __restrict__ w_pair,
                                               const int* __restrict__ pos,
                                               const float* __restrict__ aterm,
                                               const float* __restrict__ bterm,
                                               const int* __restrict__ span_ranges,
                                               float* __restrict__ out_probs,
                                               float4* __restrict__ out_ranges) {
  __shared__ float red[3 * 64 * 13];  // partials of waves 1..3, padded

  int lane = threadIdx.x & 63;
  int wv = threadIdx.x >> 6;          // wave in block: K-chunk index
  int blk = blockIdx.x;               // 0..799
  int b = blk / 100;
  int t = blk - b * 100;
  int ti = t / 10;                    // i-tile (rows; A side = x_i .* w3_c)
  int tj = t - ti * 10;               // j-tile (cols; B side = x_j)
  int quad = lane >> 4;
  int l16 = lane & 15;

  const int* posb = pos + b * M_;
  int pa = posb[ti * 16 + l16];
  int pb = posb[tj * 16 + l16];
  const float* xa = x + ((size_t)(b * N_ + pa)) * D_ + wv * 192 + quad * 8;
  const float* xb = x + ((size_t)(b * N_ + pb)) * D_ + wv * 192 + quad * 8;
  const float* w3 = w_pair + 2 * D_ * 3;

  floatx4 acc0 = {0.f, 0.f, 0.f, 0.f};
  floatx4 acc1 = {0.f, 0.f, 0.f, 0.f};
  floatx4 acc2 = {0.f, 0.f, 0.f, 0.f};

#pragma unroll
  for (int k = 0; k < 192; k += 32) {
    float af[8], bfv[8], wv24[24];
    *(float4*)(af + 0) = *(const float4*)(xa + k + 0);
    *(float4*)(af + 4) = *(const float4*)(xa + k + 4);
    *(float4*)(bfv + 0) = *(const float4*)(xb + k + 0);
    *(float4*)(bfv + 4) = *(const float4*)(xb + k + 4);
    const float* wp = w3 + (size_t)(wv * 192 + k + quad * 8) * 3;
#pragma unroll
    for (int q = 0; q < 6; ++q) *(float4*)(wv24 + 4 * q) = *(const float4*)(wp + 4 * q);

    short8 bh;
#pragma unroll
    for (int e = 0; e < 8; ++e) bh[e] = (short)(__float_as_uint(bfv[e]) >> 16);

#pragma unroll
    for (int c = 0; c < 3; ++c) {
      short8 h;
#pragma unroll
      for (int e = 0; e < 8; ++e)
        h[e] = (short)(__float_as_uint(af[e] * wv24[e * 3 + c]) >> 16);
      floatx4 acc = (c == 0) ? acc0 : (c == 1) ? acc1 : acc2;
      acc = __builtin_amdgcn_mfma_f32_16x16x32_bf16(h, bh, acc, 0, 0, 0);
      if (c == 0) acc0 = acc; else if (c == 1) acc1 = acc; else acc2 = acc;
    }
  }

  // Cross-wave reduction: waves 1..3 park partials in LDS, wave 0 sums.
  if (wv > 0) {
    int base = ((wv - 1) * 64 + lane) * 13;
#pragma unroll
    for (int r = 0; r < 4; ++r) {
      red[base + r] = acc0[r];
      red[base + 4 + r] = acc1[r];
      red[base + 8 + r] = acc2[r];
    }
  }
  __syncthreads();
  if (wv != 0) return;

#pragma unroll
  for (int u = 0; u < 3; ++u) {
    int base = (u * 64 + lane) * 13;
#pragma unroll
    for (int r = 0; r < 4; ++r) {
      acc0[r] += red[base + r];
      acc1[r] += red[base + 4 + r];
      acc2[r] += red[base + 8 + r];
    }
  }

  // Epilogue. C/D layout: col = lane&15 (j), row = quad*4 + reg (i).
  const float* at = aterm + (size_t)(b * N_) * 3;
  const float* bt = bterm + (size_t)(b * N_) * 3;
  int j = tj * 16 + l16;
  float bj0 = bt[pb * 3 + 0], bj1 = bt[pb * 3 + 1], bj2 = bt[pb * 3 + 2];
  int rj0 = span_ranges[pb * 2 + 0], rj1 = span_ranges[pb * 2 + 1];

#pragma unroll
  for (int r = 0; r < 4; ++r) {
    int i = ti * 16 + quad * 4 + r;
    if (i == j) continue;
    int pi = posb[i];
    float l0 = acc0[r] + at[pi * 3 + 0] + bj0;
    float l1 = acc1[r] + at[pi * 3 + 1] + bj1;
    float l2 = acc2[r] + at[pi * 3 + 2] + bj2;
    float s0 = 1.0f / (1.0f + expf(-l0));
    float s1 = 1.0f / (1.0f + expf(-l1));
    float s2 = 1.0f / (1.0f + expf(-l2));
    float e0 = expf(s0), e1 = expf(s1), e2 = expf(s2);
    float inv = 1.0f / (e0 + e1 + e2);
    int jj = j - (j > i ? 1 : 0);
    size_t p = (size_t)b * PAIRS_ + (size_t)i * (M_ - 1) + jj;
    out_probs[p * 3 + 0] = e0 * inv;
    out_probs[p * 3 + 1] = e1 * inv;
    out_probs[p * 3 + 2] = e2 * inv;
    float4 rg;
    rg.x = (float)span_ranges[pi * 2 + 0];
    rg.y = (float)span_ranges[pi * 2 + 1];
    rg.z = (float)rj0;
    rg.w = (float)rj1;
    out_ranges[p] = rg;
  }
}

// ---------------------------------------------------------------------------
extern "C" void kernel_launch(void* const* d_in, const int* in_sizes, int n_in,
                              void* d_out, int out_size, void* d_ws, size_t ws_size,
                              hipStream_t stream) {
  const float* x = (const float*)d_in[0];
  const float* w_span = (const float*)d_in[1];
  // d_in[2] = b_span: constant shift, irrelevant to the ranking -> unused.
  const float* w_pair = (const float*)d_in[3];
  const float* b_pair = (const float*)d_in[4];
  const int* span_ranges = (const int*)d_in[5];

  char* ws = (char*)d_ws;
  double* z = (double*)ws;
  int* pos = (int*)(ws + 25600);
  float* aterm = (float*)(ws + 30720);
  float* bterm = (float*)(ws + 69120);

  float* out = (float*)d_out;
  float* out_probs = out;                                         // B*P*3 floats
  float4* out_ranges = (float4*)(out + (size_t)B_ * PAIRS_ * 3);  // B*P*4 floats

  k_span_ab<<<(B_ * N_) / 4, 256, 0, stream>>>(x, w_span, w_pair, b_pair, z,
                                               aterm, bterm);
  k_rank<<<B_, 256, 0, stream>>>(z, pos);
  k_pairs<<<B_ * 100, 256, 0, stream>>>(x, w_pair, pos, aterm, bterm,
                                        span_ranges, out_probs, out_ranges);
}